// Round 3
// baseline (346.666 us; speedup 1.0000x reference)
//
#include <hip/hip_runtime.h>
#include <hip/hip_cooperative_groups.h>
#include <cstdint>
#include <cstddef>

namespace cg = cooperative_groups;

#define B_SZ   8
#define SEQ    4096
#define HID    1024
#define NCH    8         // snn time chunks
#define CHUNK  512       // SEQ / NCH
#define WARM   256       // warm-up steps; 0.9^256 contraction + spike-reset collapse => bit-exact
#define JTAP   16        // truncated SSM impulse-response taps
#define YTS    128       // phase-2/3 t-tile per block (256 blocks = 8 b x 32 tiles)

typedef float vfloat4 __attribute__((ext_vector_type(4)));

// ws layout: u64 spk[B_SZ*16*SEQ] = 4 MB at offset 0
__device__ __forceinline__ void snn_step(float& v, float& r, float xv, bool& s) {
  // match reference rounding: separate mul + add (no FMA contraction)
  v = __fadd_rn(__fmul_rn(v, 0.9f), xv);
  s = (r <= 0.0f) && (v >= 1.0f);
  v = s ? 0.0f : v;
  r = s ? 5.0f : fmaxf(r - 1.0f, 0.0f);
}

__device__ __forceinline__ void proc32_emit(const float* xv, float& v, float& r, int lane,
                                            unsigned long long* __restrict__ sp, int t) {
  unsigned long long my = 0;
  #pragma unroll
  for (int k = 0; k < 32; ++k) {
    bool s; snn_step(v, r, xv[k], s);
    unsigned long long m = __ballot(s);
    my = ((lane & 31) == k) ? m : my;
  }
  if (lane < 32) sp[t + lane] = my;     // 256B coalesced burst per 32 steps
}

__device__ __forceinline__ void proc32_warm(const float* xv, float& v, float& r) {
  #pragma unroll
  for (int k = 0; k < 32; ++k) { bool s; snn_step(v, r, xv[k], s); }
}

// Single cooperative kernel: grid = 256 blocks (1/CU, co-resident), 256 threads.
// Phase 1: LIF scan (identical math/layout to the 3-kernel version).
// grid.sync()
// Phase 2: per (b, 128-t tile): Krylov taps (wave0) || spk tile staging (waves 1-3),
//          popcount u, 16-tap conv -> sy in LDS.
// Phase 3: 512 KB contiguous stream-out per block.
__global__ __launch_bounds__(256) void fused_kernel(const float* __restrict__ x,
                                                    const float* __restrict__ A,
                                                    const float* __restrict__ Bv,
                                                    const float* __restrict__ Cv,
                                                    const float* __restrict__ Dp,
                                                    unsigned long long* __restrict__ spk,
                                                    vfloat4* __restrict__ out) {
  __shared__ unsigned long long lm[YTS + JTAP][17];   // [144][17] u64, pad 17: ~19.6 KB
  __shared__ float ws[JTAP];
  __shared__ float su[YTS + JTAP];
  __shared__ float sy[YTS];

  const int tid = threadIdx.x;
  const int bi  = blockIdx.x;

  // ---------------- Phase 1: LIF scan ----------------
  {
    const int hidq = bi & 3;               // hid quarter 0..3
    const int b    = (bi >> 2) & 7;
    const int c    = bi >> 5;              // chunk 0..7
    const int hid  = hidq * 256 + tid;
    const int lane = tid & 63;
    const int wv   = hid >> 6;             // global hid-wave index 0..15
    const int t0   = c * CHUNK;
    const int t1   = t0 + CHUNK;
    const int tw   = (t0 >= WARM) ? (t0 - WARM) : 0;  // len in {512, 768}, %64==0
    const float* __restrict__ xp = x + (size_t)(b * SEQ) * HID + hid;
    unsigned long long* __restrict__ sp = spk + (size_t)(b * 16 + wv) * SEQ;

    float v = 0.0f, r = 0.0f;
    float xa[32], xb[32];

    #pragma unroll
    for (int k = 0; k < 32; ++k) xa[k] = xp[(size_t)(tw + k) * HID];

    for (int t = tw; t < t1; t += 64) {
      #pragma unroll
      for (int k = 0; k < 32; ++k) xb[k] = xp[(size_t)(t + 32 + k) * HID];

      if (t >= t0) proc32_emit(xa, v, r, lane, sp, t);
      else         proc32_warm(xa, v, r);

      if (t + 64 < t1) {
        #pragma unroll
        for (int k = 0; k < 32; ++k) xa[k] = xp[(size_t)(t + 64 + k) * HID];
      }

      if (t + 32 >= t0) proc32_emit(xb, v, r, lane, sp, t + 32);
      else              proc32_warm(xb, v, r);
    }
  }

  // make spk visible device-wide, then grid-wide barrier
  __threadfence();
  cg::this_grid().sync();
  __threadfence();

  // ---------------- Phase 2: taps + u + conv ----------------
  const int b2 = bi >> 5;                  // 0..7
  const int t0 = (bi & 31) * YTS;          // tile start
  const unsigned long long* __restrict__ sb = spk + (size_t)b2 * 16 * SEQ;

  if (tid < 64) {
    // wave 0: w_m = C . A^m . B via Krylov iteration (verbatim)
    const int lane = tid;
    float arow[64];
    #pragma unroll 8
    for (int s2 = 0; s2 < 64; ++s2) arow[s2] = A[lane * 64 + s2];
    float p = Bv[lane];
    const float cv = Cv[lane];
    for (int m = 0; m < JTAP; ++m) {
      float t = cv * p;
      #pragma unroll
      for (int off = 32; off; off >>= 1) t += __shfl_xor(t, off);
      if (lane == 0) ws[m] = t;
      float n0 = 0.f, n1 = 0.f, n2 = 0.f, n3 = 0.f;
      #pragma unroll
      for (int s2 = 0; s2 < 64; s2 += 4) {
        n0 = fmaf(arow[s2 + 0], __shfl(p, s2 + 0), n0);
        n1 = fmaf(arow[s2 + 1], __shfl(p, s2 + 1), n1);
        n2 = fmaf(arow[s2 + 2], __shfl(p, s2 + 2), n2);
        n3 = fmaf(arow[s2 + 3], __shfl(p, s2 + 3), n3);
      }
      p = (n0 + n1) + (n2 + n3);
    }
  } else {
    // waves 1-3 (192 threads): stage 16 wv x 144 t masks into LDS
    const int j  = tid - 64;               // 0..191
    const int wv = j & 15;
    const int i0 = (j >> 4) * 12;          // 12 groups x 12 t each
    #pragma unroll
    for (int s = 0; s < 12; ++s) {
      const int i = i0 + s;
      const int t = t0 - JTAP + i;
      lm[i][wv] = (t >= 0) ? sb[(size_t)wv * SEQ + t] : 0ull;
    }
  }
  __syncthreads();

  if (tid < YTS + JTAP) {
    int cc = 0;
    #pragma unroll
    for (int wv = 0; wv < 16; ++wv) cc += __popcll(lm[tid][wv]);
    su[tid] = cc * (1.0f / 1024.0f);
  }
  __syncthreads();

  if (tid < YTS) {
    float acc = Dp[0] * su[JTAP + tid];
    #pragma unroll
    for (int m = 0; m < JTAP; ++m) acc = fmaf(ws[m], su[JTAP + tid - m], acc);
    sy[tid] = acc;
  }
  __syncthreads();

  // ---------------- Phase 3: stream out (512 KB contiguous per block) ----------------
  const int wv = tid >> 4;
  const int sh = (tid & 15) * 4;
  vfloat4* op = out + (size_t)(b2 * SEQ + t0) * 256 + tid;
  #pragma unroll 8
  for (int j = 0; j < YTS; ++j) {
    const unsigned long long m = lm[JTAP + j][wv];
    const float yv = sy[j];
    vfloat4 o;
    o.x = ((m >> (sh + 0)) & 1ull) ? 1.0f + yv : yv;
    o.y = ((m >> (sh + 1)) & 1ull) ? 1.0f + yv : yv;
    o.z = ((m >> (sh + 2)) & 1ull) ? 1.0f + yv : yv;
    o.w = ((m >> (sh + 3)) & 1ull) ? 1.0f + yv : yv;
    op[(size_t)j * 256] = o;
  }
}

extern "C" void kernel_launch(void* const* d_in, const int* in_sizes, int n_in,
                              void* d_out, int out_size, void* d_ws, size_t ws_size,
                              hipStream_t stream) {
  const float* x  = (const float*)d_in[0];   // (8, 4096, 1024)
  const float* A  = (const float*)d_in[1];   // (64, 64)
  const float* Bv = (const float*)d_in[2];   // (64, 1)
  const float* Cv = (const float*)d_in[3];   // (1, 64)
  const float* Dp = (const float*)d_in[4];   // (1, 1)

  unsigned long long* spk = (unsigned long long*)d_ws;   // 4 MB
  vfloat4* outp = (vfloat4*)d_out;

  void* args[] = {(void*)&x, (void*)&A, (void*)&Bv, (void*)&Cv, (void*)&Dp,
                  (void*)&spk, (void*)&outp};
  hipLaunchCooperativeKernel((const void*)fused_kernel, dim3(256), dim3(256),
                             args, 0, stream);
}